// Round 1
// baseline (184.217 us; speedup 1.0000x reference)
//
#include <hip/hip_runtime.h>

#define TT 512
#define LL 64
#define BB 16
#define NN 20
#define DTC 0.01f
#define NOISEC 1e-3f
#define LN2C 0.69314718056f

// ws[0..63] = rowsum(pathloss), ws[64..127] = diag(pathloss)
__global__ void prep_kernel(const float* __restrict__ pathloss, float* __restrict__ ws) {
    int l = threadIdx.x;  // 64 threads
    float s = 0.f;
    #pragma unroll
    for (int j = 0; j < LL; ++j) s += pathloss[l * LL + j];
    ws[l] = s;
    ws[LL + l] = pathloss[l * LL + l];
}

// One block per channel c = b*64 + l. 256 threads = 4 waves.
// Chain of 19 causal convolutions with time-reversed kernels (matches XLA
// cross-correlation, pad (T-1,T-1), keep out[:T]).
// qrevPad[v] (v in [0,1024)): v<512 -> 0 (triangle masking for free),
// v = 512+d -> q_n[511-d]. Stored residue-split: qr8[v&7][v>>3] so the
// per-m fresh read is stride-1 across lanes (no bank conflicts).
__global__ __launch_bounds__(256) void outage_kernel(
    const float* __restrict__ powers,
    const float* __restrict__ ws,
    float* __restrict__ out)
{
    __shared__ float Qs[TT];          // current Q_n
    __shared__ float qr8[8][128];     // residue-split zero-padded reversed kernel
    __shared__ float partial[4][TT];  // per-wave partial sums (m-range split)

    const int tid  = threadIdx.x;
    const int wave = tid >> 6;
    const int lane = tid & 63;
    const int c = blockIdx.x;
    const int b = c >> 6;
    const int l = c & 63;

    const float rs = ws[l];
    const float dg = ws[LL + l];
    const float dsum = rs - dg;

    // each thread owns two time indices
    const int tau0 = tid;
    const int tau1 = tid + 256;
    const float p2a = exp2f(tau0 * DTC);   // 2^{t}
    const float p2b = exp2f(tau1 * DTC);
    const float p1a = p2a - 1.f;           // 2^{t} - 1
    const float p1b = p2b - 1.f;

    // zero the padding half of qr8 (flat v in [0,512) -> qr8[v>>6? no:]
    // flat idx in [0,512): row = idx>>6 in [0,8), col = idx&63 in [0,64)
    qr8[tau0 >> 6][tau0 & 63] = 0.f;
    qr8[tau1 >> 6][tau1 & 63] = 0.f;

    // Q_0 = Q1 = 1 - exp(-(2^t - 1) * sinr_0)
    {
        float p  = powers[(b * NN + 0) * LL + l];
        float s0 = dg * p / (p * dsum + NOISEC);
        Qs[tau0] = 1.f - expf(-p1a * s0);
        Qs[tau1] = 1.f - expf(-p1b * s0);
    }
    __syncthreads();

    float lossCh = 0.f;
    if (tid == 0) {
        // 1 (RHO*D base) + power[b,0,l] (E base) + (power[b,1,l]+1)*Q_0[511]
        lossCh = 1.f + powers[(b * NN + 0) * LL + l]
               + (powers[(b * NN + 1) * LL + l] + 1.f) * Qs[TT - 1];
    }

    const int m0    = wave << 7;              // this wave's m-range start
    const int initJ = 64 - (wave << 4) + lane;

    for (int n = 1; n < NN; ++n) {
        // ---- fill reversed kernel for step n ----
        {
            float p = powers[(b * NN + n) * LL + l];
            float s = dg * p / (p * dsum + NOISEC);
            float q0 = expf(-p1a * s) * p2a * s * LN2C;
            float q1 = expf(-p1b * s) * p2b * s * LN2C;
            int v0 = 1023 - tau0;   // data region v >= 512 only; zeros persist
            int v1 = 1023 - tau1;
            qr8[v0 & 7][v0 >> 3] = q0;
            qr8[v1 & 7][v1 >> 3] = q1;
        }
        __syncthreads();

        // ---- accumulate: lane owns outputs t = 8*lane .. 8*lane+7,
        //      wave owns m in [m0, m0+128) ----
        float acc[8];
        #pragma unroll
        for (int r = 0; r < 8; ++r) acc[r] = 0.f;
        float W[8];   // W[r] = qrevPad[512 + 8*lane + r - m]
        #pragma unroll
        for (int r = 0; r < 8; ++r) W[r] = qr8[r][initJ];

        for (int mb = 0; mb < 128; mb += 8) {
            const int baseJ = 63 - (wave << 4) - (mb >> 3) + lane;
            #pragma unroll
            for (int i = 0; i < 8; ++i) {
                float Qm = Qs[m0 + mb + i];           // broadcast (uniform addr)
                #pragma unroll
                for (int r = 0; r < 8; ++r) acc[r] = fmaf(Qm, W[r], acc[r]);
                // fresh element: v = 8*lane + (511 - m); residue = 7-i (const)
                float fresh = qr8[7 - i][baseJ];
                #pragma unroll
                for (int r = 7; r >= 1; --r) W[r] = W[r - 1];
                W[0] = fresh;
            }
        }

        #pragma unroll
        for (int r = 0; r < 8; ++r) partial[wave][(lane << 3) + r] = acc[r];
        __syncthreads();

        // ---- combine partials, scale by DT, write back Q ----
        {
            float v0 = (partial[0][tau0] + partial[1][tau0])
                     + (partial[2][tau0] + partial[3][tau0]);
            float v1 = (partial[0][tau1] + partial[1][tau1])
                     + (partial[2][tau1] + partial[3][tau1]);
            Qs[tau0] = v0 * DTC;
            Qs[tau1] = v1 * DTC;
        }
        __syncthreads();

        if (tid == 0) {
            float qlast = Qs[TT - 1];
            float wgt = (n < NN - 1) ? (powers[(b * NN + n + 1) * LL + l] + 1.f)
                                     : 1.f;   // LAM term for n = 19
            lossCh += wgt * qlast;
        }
    }

    if (tid == 0) atomicAdd(out, lossCh);
}

extern "C" void kernel_launch(void* const* d_in, const int* in_sizes, int n_in,
                              void* d_out, int out_size, void* d_ws, size_t ws_size,
                              hipStream_t stream) {
    const float* pathloss = (const float*)d_in[0];
    const float* powers   = (const float*)d_in[1];
    float* outp = (float*)d_out;
    float* ws   = (float*)d_ws;

    hipMemsetAsync(d_out, 0, sizeof(float) * out_size, stream);
    prep_kernel<<<1, 64, 0, stream>>>(pathloss, ws);
    outage_kernel<<<BB * LL, 256, 0, stream>>>(powers, ws, outp);
}